// Round 26
// baseline (79.005 us; speedup 1.0000x reference)
//
#include <hip/hip_runtime.h>
#include <hip/hip_bf16.h>
#include <stdint.h>

#define N_NODES 16384   // B*H*W
#define NPB     4096    // nodes per batch
#define NB      4
#define KNN     4
#define WIN     12      // sorted-order window radius for exact 1-D kNN
#define NBUK    4096

typedef short bf16x8 __attribute__((ext_vector_type(8)));
typedef float f32x4 __attribute__((ext_vector_type(4)));
typedef unsigned short u16x8 __attribute__((ext_vector_type(8)));

__device__ __forceinline__ unsigned short f2bf(float f) {
  unsigned u = __float_as_uint(f);
  unsigned r = (u + 0x7fff + ((u >> 16) & 1)) >> 16;   // RNE
  return (unsigned short)r;
}
__device__ __forceinline__ float bf2f(unsigned short u) {
  return __uint_as_float(((unsigned)u) << 16);
}

// ---- bucket stage: hist + scan + scatter + in-LDS sort ----
// One block per batch (4 x 1024). Writes sorted skeys, rank, deg=1, mask=0.
__global__ __launch_bounds__(1024)
void bucket_kernel(const float* __restrict__ dm,
                   unsigned long long* __restrict__ skeys_g,
                   int* __restrict__ rank_g,
                   int* __restrict__ deg_g,
                   unsigned* __restrict__ mask_g) {
  __shared__ int sHist[4096];
  __shared__ int sCur[4096];
  __shared__ unsigned long long sKeys[4096];  // aliases scan scratch
  int* part1 = (int*)sKeys;                   // [1024]
  int* part2 = (int*)(sKeys + 512);           // [64]
  const int t = threadIdx.x, b = blockIdx.x;
  const float* d = dm + b * NPB;

  unsigned long long kv[4]; int bk[4];
#pragma unroll
  for (int r = 0; r < 4; ++r) sHist[t + r * 1024] = 0;
  __syncthreads();
#pragma unroll
  for (int r = 0; r < 4; ++r) {
    int i = t + r * 1024;
    float v = d[i];
    kv[r] = (((unsigned long long)__float_as_uint(v)) << 32) | (unsigned)i;
    int k = (int)(v * (float)NBUK); if (k > NBUK - 1) k = NBUK - 1;
    bk[r] = k;
    atomicAdd(&sHist[k], 1);
  }
  __syncthreads();
  int c0 = sHist[4 * t + 0], c1 = sHist[4 * t + 1];
  int c2 = sHist[4 * t + 2], c3 = sHist[4 * t + 3];
  part1[t] = c0 + c1 + c2 + c3;
  __syncthreads();
  if (t < 64) {
    int s = 0;
#pragma unroll
    for (int k = 0; k < 16; ++k) s += part1[16 * t + k];
    part2[t] = s;
  }
  __syncthreads();
  if (t == 0) {
    int a = 0;
    for (int u = 0; u < 64; ++u) { int v = part2[u]; part2[u] = a; a += v; }
  }
  __syncthreads();
  int base = part2[t >> 4];
  for (int k = (t >> 4) * 16; k < t; ++k) base += part1[k];
  sHist[4 * t + 0] = base; sCur[4 * t + 0] = base; base += c0;
  sHist[4 * t + 1] = base; sCur[4 * t + 1] = base; base += c1;
  sHist[4 * t + 2] = base; sCur[4 * t + 2] = base; base += c2;
  sHist[4 * t + 3] = base; sCur[4 * t + 3] = base;
  __syncthreads();   // scan scratch dead -> sKeys writable
#pragma unroll
  for (int r = 0; r < 4; ++r) {
    int slot = atomicAdd(&sCur[bk[r]], 1);
    sKeys[slot] = kv[r];
  }
  __syncthreads();
#pragma unroll
  for (int r = 0; r < 4; ++r) {
    int g = t + r * 1024;
    int s0 = sHist[g];
    int s1 = (g == NPB - 1) ? NPB : sHist[g + 1];
    for (int i = s0 + 1; i < s1; ++i) {
      unsigned long long x = sKeys[i];
      int j = i - 1;
      while (j >= s0 && sKeys[j] > x) { sKeys[j + 1] = sKeys[j]; --j; }
      sKeys[j + 1] = x;
    }
  }
  __syncthreads();
#pragma unroll
  for (int r = 0; r < 4; ++r) {
    int i = t + r * 1024;
    unsigned long long k = sKeys[i];
    skeys_g[b * NPB + i] = k;
    rank_g[b * NPB + (int)(k & 0xffffffffull)] = i;
    deg_g[b * NPB + i] = 1;
    mask_g[b * NPB + i] = 0;
  }
}

// ---- merged cvt + WIDE select ----
// z<4: fm batch transpose -> permuted bf16 rows. z==4: id<128 weight cvt;
// id in [128,192): select (exact top-5 by (dist,idx), global atomics).
__global__ void cvtsel_kernel(const float* __restrict__ fm, unsigned short* __restrict__ px0,
                              const float* __restrict__ W1, unsigned short* __restrict__ W1t,
                              const float* __restrict__ W2, unsigned short* __restrict__ W2t,
                              const int* __restrict__ rank,
                              const unsigned long long* __restrict__ skeys,
                              int* __restrict__ deg, unsigned* __restrict__ mask) {
  __shared__ float tile[64][33];
  int z = blockIdx.z;
  const float* in; unsigned short* outbase; int Rin, Cin, r0, c0;
  bool perm = false;
  if (z < NB) {
    in = fm + (size_t)z * 256 * 4096; outbase = px0 + (size_t)z * NPB * 256;
    Rin = 256; Cin = 4096; perm = true;
    c0 = blockIdx.x * 32; r0 = blockIdx.y * 64;
  } else {
    int id = blockIdx.y * 128 + blockIdx.x;
    if (id >= 128 && id < 192) {
      // ---- select path ----
      int p = (id - 128) * 256 + threadIdx.x;   // global sorted slot
      int b = p >> 12, pl = p & (NPB - 1);
      const unsigned long long* sk = skeys + b * NPB;
      unsigned long long kp = sk[pl];
      float di = __uint_as_float((unsigned)(kp >> 32));
      int lo = pl - WIN; if (lo < 0) lo = 0;
      int hi = pl + WIN; if (hi > NPB - 1) hi = NPB - 1;
      unsigned long long k0 = ~0ull, k1 = ~0ull, k2 = ~0ull, k3 = ~0ull, k4 = ~0ull;
      for (int q = lo; q <= hi; ++q) {
        unsigned long long key = sk[q];
        float v = __uint_as_float((unsigned)(key >> 32));
        float dist = fabsf(di - v);
        unsigned long long dk = (((unsigned long long)__float_as_uint(dist)) << 24) |
                                ((key & 0xfffull) << 12) | (unsigned)q;
        if (dk < k4) {
          if (dk < k0)      { k4 = k3; k3 = k2; k2 = k1; k1 = k0; k0 = dk; }
          else if (dk < k1) { k4 = k3; k3 = k2; k2 = k1; k1 = dk; }
          else if (dk < k2) { k4 = k3; k3 = k2; k2 = dk; }
          else if (dk < k3) { k4 = k3; k3 = dk; }
          else              { k4 = dk; }
        }
      }
      int base = b * NPB;
      int t0 = (int)(k1 & 0xfff), t1 = (int)(k2 & 0xfff);
      int t2 = (int)(k3 & 0xfff), t3 = (int)(k4 & 0xfff);
      atomicAdd(&deg[base + t0], 1); atomicOr(&mask[base + t0], 1u << (pl - t0 + WIN));
      atomicAdd(&deg[base + t1], 1); atomicOr(&mask[base + t1], 1u << (pl - t1 + WIN));
      atomicAdd(&deg[base + t2], 1); atomicOr(&mask[base + t2], 1u << (pl - t2 + WIN));
      atomicAdd(&deg[base + t3], 1); atomicOr(&mask[base + t3], 1u << (pl - t3 + WIN));
      return;
    }
    if (id >= 64 && id < 128) { id -= 64; in = W2; outbase = W2t; Rin = 512; Cin = 256; c0 = (id & 7) * 32; r0 = (id >> 3) * 64; }
    else if (id < 64)         { in = W1; outbase = W1t; Rin = 256; Cin = 512; c0 = (id & 15) * 32; r0 = (id >> 4) * 64; }
    else return;
  }
  int tx = threadIdx.x & 31, ty = threadIdx.x >> 5;   // ty 0..7
  const float* ip = in + (size_t)(r0 + ty) * Cin + c0 + tx;
#pragma unroll
  for (int i = 0; i < 8; ++i) tile[ty + 8 * i][tx] = ip[(size_t)(8 * i) * Cin];
  __syncthreads();
  int orow = threadIdx.x >> 3;        // 0..31 (input col / node)
  int oseg = (threadIdx.x & 7) * 8;   // 0..56 (input row offset)
  int outrow = c0 + orow;
  if (perm) outrow = rank[(size_t)z * NPB + outrow];
  unsigned short* op = outbase + (size_t)outrow * Rin + r0 + oseg;
  u16x8 o;
#pragma unroll
  for (int k = 0; k < 8; ++k) o[k] = f2bf(tile[oseg + k][orow]);
  *(u16x8*)op = o;
}

// ---- fp32 transpose 64x64, float4 both sides: [B][4096][256] -> [B][256][4096] ----
__global__ __launch_bounds__(256)
void transpose64_kernel(const float* __restrict__ in, float* __restrict__ out) {
  __shared__ float tile[64][68];
  int cb = blockIdx.x * 64;
  int nb = blockIdx.y * 64;
  int b = blockIdx.z;
  int r = threadIdx.x >> 2, q = threadIdx.x & 3;
  const float* ip = in + ((size_t)b * NPB + nb + r) * 256 + cb;
#pragma unroll
  for (int it = 0; it < 4; ++it) {
    int c = q * 4 + it * 16;
    *(float4*)&tile[r][c] = *(const float4*)(ip + c);
  }
  __syncthreads();
  float* op = out + ((size_t)b * 256 + cb + r) * 4096 + nb;
#pragma unroll
  for (int it = 0; it < 4; ++it) {
    int n = q * 4 + it * 16;
    float4 v;
    v.x = tile[n + 0][r]; v.y = tile[n + 1][r];
    v.z = tile[n + 2][r]; v.w = tile[n + 3][r];
    *(float4*)(op + n) = v;
  }
}

// ---- mask-driven window propagate (bf16 -> bf16), 2 nodes/wave ----
__global__ void prop_kernel(const unsigned short* __restrict__ in,
                            unsigned short* __restrict__ out,
                            const unsigned* __restrict__ mask,
                            const int* __restrict__ deg) {
  int i = blockIdx.x * 8 + (threadIdx.x >> 5);
  int l = threadIdx.x & 31;
  unsigned m = mask[i];
  float a[8] = {};
#pragma unroll
  for (int off = 0; off < 2 * WIN + 1; ++off) {
    int c = ((m >> off) & 1) + (off == WIN);
    if (c) {
      int q = i + off - WIN;
      float dj = (float)c * rsqrtf((float)deg[q]);
      u16x8 u = *(const u16x8*)(in + (size_t)q * 256 + l * 8);
#pragma unroll
      for (int k = 0; k < 8; ++k) a[k] = fmaf(dj, bf2f(u[k]), a[k]);
    }
  }
  float di = rsqrtf((float)deg[i]);
  u16x8 o;
#pragma unroll
  for (int k = 0; k < 8; ++k) o[k] = f2bf(a[k] * di);
  *(u16x8*)(out + (size_t)i * 256 + l * 8) = o;
}

// ---- mask-driven propagate + bias + relu, sorted in -> ORIGINAL-order f32 out ----
__global__ void prop2_kernel(const unsigned short* __restrict__ in,
                             float* __restrict__ out,
                             const unsigned* __restrict__ mask,
                             const int* __restrict__ deg,
                             const float* __restrict__ bias,
                             const unsigned long long* __restrict__ skeys) {
  int i = blockIdx.x * 8 + (threadIdx.x >> 5);
  int l = threadIdx.x & 31;
  unsigned m = mask[i];
  float a[8] = {};
#pragma unroll
  for (int off = 0; off < 2 * WIN + 1; ++off) {
    int c = ((m >> off) & 1) + (off == WIN);
    if (c) {
      int q = i + off - WIN;
      float dj = (float)c * rsqrtf((float)deg[q]);
      u16x8 u = *(const u16x8*)(in + (size_t)q * 256 + l * 8);
#pragma unroll
      for (int k = 0; k < 8; ++k) a[k] = fmaf(dj, bf2f(u[k]), a[k]);
    }
  }
  float di = rsqrtf((float)deg[i]);
  int node = (i & ~(NPB - 1)) + (int)(skeys[i] & 0xffffffffull);   // un-permute
  float4 o0, o1;
  o0.x = fmaxf(a[0] * di + bias[l * 8 + 0], 0.f);
  o0.y = fmaxf(a[1] * di + bias[l * 8 + 1], 0.f);
  o0.z = fmaxf(a[2] * di + bias[l * 8 + 2], 0.f);
  o0.w = fmaxf(a[3] * di + bias[l * 8 + 3], 0.f);
  o1.x = fmaxf(a[4] * di + bias[l * 8 + 4], 0.f);
  o1.y = fmaxf(a[5] * di + bias[l * 8 + 5], 0.f);
  o1.z = fmaxf(a[6] * di + bias[l * 8 + 6], 0.f);
  o1.w = fmaxf(a[7] * di + bias[l * 8 + 7], 0.f);
  *(float4*)(out + (size_t)node * 256 + l * 8) = o0;
  *(float4*)(out + (size_t)node * 256 + l * 8 + 4) = o1;
}

// ---- bf16 MFMA GEMM, 64x64 tile, BK=256 FULL-K staging (64KB LDS) ----
// gemm1 (K=256): single stage, zero inner barriers. gemm2 (K=512): 2 iters.
// Rows are 512B (256 bf16 = 32 chunks of 16B); swizzle pc = gc ^ (r&7).
template <bool BIAS_RELU>
__global__ __launch_bounds__(256)
void gemm_bf16_kernel(const unsigned short* __restrict__ A,
                      const unsigned short* __restrict__ Bt,
                      unsigned short* __restrict__ C, const float* __restrict__ bias,
                      int M, int N, int K) {
  __shared__ char lds[65536];   // A: [64][512B] @0 ; B: [64][512B] @32768
  const int tid = threadIdx.x;
  const int l = tid & 63, w = tid >> 6;
  const int bm = blockIdx.x * 64, bn = blockIdx.y * 64;
  f32x4 acc[4] = {};

  for (int k0 = 0; k0 < K; k0 += 256) {
    __syncthreads();
#pragma unroll
    for (int q = 0; q < 8; ++q) {          // A 32KB + B 32KB
      int o = q * 4096 + tid * 16;
      int r = o >> 9;                      // 0..63
      int gc = ((o >> 4) & 31) ^ (r & 7);
      const char* srcA = (const char*)A + ((size_t)(bm + r) * K + k0) * 2 + gc * 16;
      __builtin_amdgcn_global_load_lds(
          (const __attribute__((address_space(1))) void*)srcA,
          (__attribute__((address_space(3))) void*)(lds + o), 16, 0, 0);
      const char* srcB = (const char*)Bt + ((size_t)(bn + r) * K + k0) * 2 + gc * 16;
      __builtin_amdgcn_global_load_lds(
          (const __attribute__((address_space(1))) void*)srcB,
          (__attribute__((address_space(3))) void*)(lds + 32768 + o), 16, 0, 0);
    }
    __syncthreads();

#pragma unroll
    for (int kk = 0; kk < 256; kk += 32) {
      bf16x8 af[4], bf;
      int gc = (kk >> 3) + (l >> 4);
#pragma unroll
      for (int mi = 0; mi < 4; ++mi) {
        int r = mi * 16 + (l & 15);
        af[mi] = *(const bf16x8*)(lds + r * 512 + ((gc ^ (r & 7)) << 4));
      }
      {
        int r = w * 16 + (l & 15);
        bf = *(const bf16x8*)(lds + 32768 + r * 512 + ((gc ^ (r & 7)) << 4));
      }
#pragma unroll
      for (int mi = 0; mi < 4; ++mi)
        acc[mi] = __builtin_amdgcn_mfma_f32_16x16x32_bf16(af[mi], bf, acc[mi], 0, 0, 0);
    }
  }

#pragma unroll
  for (int mi = 0; mi < 4; ++mi) {
    int row0 = bm + mi * 16 + ((l >> 4) << 2);
    int col = bn + w * 16 + (l & 15);
    float bv = BIAS_RELU ? bias[col] : 0.f;
    f32x4 v = acc[mi];
#pragma unroll
    for (int r = 0; r < 4; ++r) {
      float val = v[r];
      if (BIAS_RELU) val = fmaxf(val + bv, 0.f);
      C[(size_t)(row0 + r) * N + col] = f2bf(val);
    }
  }
}

// ---- launch ----
extern "C" void kernel_launch(void* const* d_in, const int* in_sizes, int n_in,
                              void* d_out, int out_size, void* d_ws, size_t ws_size,
                              hipStream_t stream) {
  const float* dm = (const float*)d_in[0];
  const float* fm = (const float*)d_in[1];
  const float* W1 = (const float*)d_in[2];
  const float* b1 = (const float*)d_in[3];
  const float* W2 = (const float*)d_in[4];
  const float* b2 = (const float*)d_in[5];
  float* out = (float*)d_out;

  char* ws = (char*)d_ws;
  int*                deg   = (int*)(ws + 0x040000);               // 64KB
  unsigned*           mask  = (unsigned*)(ws + 0x060000);          // 64KB
  unsigned long long* skeys = (unsigned long long*)(ws + 0x100000);// 128KB
  int*                rank  = (int*)(ws + 0x130000);               // 64KB
  unsigned short*     W1t   = (unsigned short*)(ws + 0x190000);    // 256KB
  unsigned short*     W2t   = (unsigned short*)(ws + 0x1D0000);    // 256KB
  unsigned short*     px0   = (unsigned short*)(ws + 0x0400000);   // 8MB (sorted space)
  unsigned short*     px    = (unsigned short*)(ws + 0x0C00000);   // 8MB (sorted space)
  unsigned short*     h1    = (unsigned short*)(ws + 0x1400000);   // 16MB (sorted space)
  unsigned short*     t2    = (unsigned short*)(ws + 0x2400000);   // 8MB (sorted space)
  float*              xout  = (float*)(ws + 0x2C00000);            // 16MB (original order)
  (void)ws_size; (void)in_sizes; (void)n_in; (void)out_size;

  // graph build: sort (4-CU), then merged {cvt + WIDE select} launch
  bucket_kernel<<<NB, 1024, 0, stream>>>(dm, skeys, rank, deg, mask);
  cvtsel_kernel<<<dim3(128, 4, NB + 1), 256, 0, stream>>>(
      fm, px0, W1, W1t, W2, W2t, rank, skeys, deg, mask);

  // layer 1 (sorted space): mask propagate, then full-K GEMM -> bf16
  prop_kernel<<<N_NODES / 8, 256, 0, stream>>>(px0, px, mask, deg);
  gemm_bf16_kernel<true><<<dim3(256, 8), 256, 0, stream>>>(
      px, W1t, h1, b1, 16384, 512, 256);

  // layer 2: full-K GEMM h1@W2 -> bf16, mask propagate + un-permute -> f32
  gemm_bf16_kernel<false><<<dim3(256, 4), 256, 0, stream>>>(
      h1, W2t, t2, nullptr, 16384, 256, 512);
  prop2_kernel<<<N_NODES / 8, 256, 0, stream>>>(t2, xout, mask, deg, b2, skeys);

  // node-major -> [B][256][4096] (64x64 float4 transpose)
  transpose64_kernel<<<dim3(4, 64, NB), 256, 0, stream>>>(xout, out);
}

// Round 27
// 74.739 us; speedup vs baseline: 1.0571x; 1.0571x over previous
//
#include <hip/hip_runtime.h>
#include <hip/hip_bf16.h>
#include <stdint.h>

#define N_NODES 16384   // B*H*W
#define NPB     4096    // nodes per batch
#define NB      4
#define KNN     4
#define WIN     12      // sorted-order window radius for exact 1-D kNN
#define NBUK    4096

typedef short bf16x8 __attribute__((ext_vector_type(8)));
typedef float f32x4 __attribute__((ext_vector_type(4)));
typedef unsigned short u16x8 __attribute__((ext_vector_type(8)));

__device__ __forceinline__ unsigned short f2bf(float f) {
  unsigned u = __float_as_uint(f);
  unsigned r = (u + 0x7fff + ((u >> 16) & 1)) >> 16;   // RNE
  return (unsigned short)r;
}
__device__ __forceinline__ float bf2f(unsigned short u) {
  return __uint_as_float(((unsigned)u) << 16);
}

// ---- bucket stage: hist + scan + scatter + in-LDS sort ----
__global__ __launch_bounds__(1024)
void bucket_kernel(const float* __restrict__ dm,
                   unsigned long long* __restrict__ skeys_g,
                   int* __restrict__ rank_g,
                   int* __restrict__ deg_g,
                   unsigned* __restrict__ mask_g) {
  __shared__ int sHist[4096];
  __shared__ int sCur[4096];
  __shared__ unsigned long long sKeys[4096];  // aliases scan scratch
  int* part1 = (int*)sKeys;                   // [1024]
  int* part2 = (int*)(sKeys + 512);           // [64]
  const int t = threadIdx.x, b = blockIdx.x;
  const float* d = dm + b * NPB;

  unsigned long long kv[4]; int bk[4];
#pragma unroll
  for (int r = 0; r < 4; ++r) sHist[t + r * 1024] = 0;
  __syncthreads();
#pragma unroll
  for (int r = 0; r < 4; ++r) {
    int i = t + r * 1024;
    float v = d[i];
    kv[r] = (((unsigned long long)__float_as_uint(v)) << 32) | (unsigned)i;
    int k = (int)(v * (float)NBUK); if (k > NBUK - 1) k = NBUK - 1;
    bk[r] = k;
    atomicAdd(&sHist[k], 1);
  }
  __syncthreads();
  int c0 = sHist[4 * t + 0], c1 = sHist[4 * t + 1];
  int c2 = sHist[4 * t + 2], c3 = sHist[4 * t + 3];
  part1[t] = c0 + c1 + c2 + c3;
  __syncthreads();
  if (t < 64) {
    int s = 0;
#pragma unroll
    for (int k = 0; k < 16; ++k) s += part1[16 * t + k];
    part2[t] = s;
  }
  __syncthreads();
  if (t == 0) {
    int a = 0;
    for (int u = 0; u < 64; ++u) { int v = part2[u]; part2[u] = a; a += v; }
  }
  __syncthreads();
  int base = part2[t >> 4];
  for (int k = (t >> 4) * 16; k < t; ++k) base += part1[k];
  sHist[4 * t + 0] = base; sCur[4 * t + 0] = base; base += c0;
  sHist[4 * t + 1] = base; sCur[4 * t + 1] = base; base += c1;
  sHist[4 * t + 2] = base; sCur[4 * t + 2] = base; base += c2;
  sHist[4 * t + 3] = base; sCur[4 * t + 3] = base;
  __syncthreads();   // scan scratch dead -> sKeys writable
#pragma unroll
  for (int r = 0; r < 4; ++r) {
    int slot = atomicAdd(&sCur[bk[r]], 1);
    sKeys[slot] = kv[r];
  }
  __syncthreads();
#pragma unroll
  for (int r = 0; r < 4; ++r) {
    int g = t + r * 1024;
    int s0 = sHist[g];
    int s1 = (g == NPB - 1) ? NPB : sHist[g + 1];
    for (int i = s0 + 1; i < s1; ++i) {
      unsigned long long x = sKeys[i];
      int j = i - 1;
      while (j >= s0 && sKeys[j] > x) { sKeys[j + 1] = sKeys[j]; --j; }
      sKeys[j + 1] = x;
    }
  }
  __syncthreads();
#pragma unroll
  for (int r = 0; r < 4; ++r) {
    int i = t + r * 1024;
    unsigned long long k = sKeys[i];
    skeys_g[b * NPB + i] = k;
    rank_g[b * NPB + (int)(k & 0xffffffffull)] = i;
    deg_g[b * NPB + i] = 1;
    mask_g[b * NPB + i] = 0;
  }
}

// ---- merged cvt + WIDE select ----
__global__ void cvtsel_kernel(const float* __restrict__ fm, unsigned short* __restrict__ px0,
                              const float* __restrict__ W1, unsigned short* __restrict__ W1t,
                              const float* __restrict__ W2, unsigned short* __restrict__ W2t,
                              const int* __restrict__ rank,
                              const unsigned long long* __restrict__ skeys,
                              int* __restrict__ deg, unsigned* __restrict__ mask) {
  __shared__ float tile[64][33];
  int z = blockIdx.z;
  const float* in; unsigned short* outbase; int Rin, Cin, r0, c0;
  bool perm = false;
  if (z < NB) {
    in = fm + (size_t)z * 256 * 4096; outbase = px0 + (size_t)z * NPB * 256;
    Rin = 256; Cin = 4096; perm = true;
    c0 = blockIdx.x * 32; r0 = blockIdx.y * 64;
  } else {
    int id = blockIdx.y * 128 + blockIdx.x;
    if (id >= 128 && id < 192) {
      // ---- select path ----
      int p = (id - 128) * 256 + threadIdx.x;   // global sorted slot
      int b = p >> 12, pl = p & (NPB - 1);
      const unsigned long long* sk = skeys + b * NPB;
      unsigned long long kp = sk[pl];
      float di = __uint_as_float((unsigned)(kp >> 32));
      int lo = pl - WIN; if (lo < 0) lo = 0;
      int hi = pl + WIN; if (hi > NPB - 1) hi = NPB - 1;
      unsigned long long k0 = ~0ull, k1 = ~0ull, k2 = ~0ull, k3 = ~0ull, k4 = ~0ull;
      for (int q = lo; q <= hi; ++q) {
        unsigned long long key = sk[q];
        float v = __uint_as_float((unsigned)(key >> 32));
        float dist = fabsf(di - v);
        unsigned long long dk = (((unsigned long long)__float_as_uint(dist)) << 24) |
                                ((key & 0xfffull) << 12) | (unsigned)q;
        if (dk < k4) {
          if (dk < k0)      { k4 = k3; k3 = k2; k2 = k1; k1 = k0; k0 = dk; }
          else if (dk < k1) { k4 = k3; k3 = k2; k2 = k1; k1 = dk; }
          else if (dk < k2) { k4 = k3; k3 = k2; k2 = dk; }
          else if (dk < k3) { k4 = k3; k3 = dk; }
          else              { k4 = dk; }
        }
      }
      int base = b * NPB;
      int t0 = (int)(k1 & 0xfff), t1 = (int)(k2 & 0xfff);
      int t2 = (int)(k3 & 0xfff), t3 = (int)(k4 & 0xfff);
      atomicAdd(&deg[base + t0], 1); atomicOr(&mask[base + t0], 1u << (pl - t0 + WIN));
      atomicAdd(&deg[base + t1], 1); atomicOr(&mask[base + t1], 1u << (pl - t1 + WIN));
      atomicAdd(&deg[base + t2], 1); atomicOr(&mask[base + t2], 1u << (pl - t2 + WIN));
      atomicAdd(&deg[base + t3], 1); atomicOr(&mask[base + t3], 1u << (pl - t3 + WIN));
      return;
    }
    if (id >= 64 && id < 128) { id -= 64; in = W2; outbase = W2t; Rin = 512; Cin = 256; c0 = (id & 7) * 32; r0 = (id >> 3) * 64; }
    else if (id < 64)         { in = W1; outbase = W1t; Rin = 256; Cin = 512; c0 = (id & 15) * 32; r0 = (id >> 4) * 64; }
    else return;
  }
  int tx = threadIdx.x & 31, ty = threadIdx.x >> 5;   // ty 0..7
  const float* ip = in + (size_t)(r0 + ty) * Cin + c0 + tx;
#pragma unroll
  for (int i = 0; i < 8; ++i) tile[ty + 8 * i][tx] = ip[(size_t)(8 * i) * Cin];
  __syncthreads();
  int orow = threadIdx.x >> 3;        // 0..31 (input col / node)
  int oseg = (threadIdx.x & 7) * 8;   // 0..56 (input row offset)
  int outrow = c0 + orow;
  if (perm) outrow = rank[(size_t)z * NPB + outrow];
  unsigned short* op = outbase + (size_t)outrow * Rin + r0 + oseg;
  u16x8 o;
#pragma unroll
  for (int k = 0; k < 8; ++k) o[k] = f2bf(tile[oseg + k][orow]);
  *(u16x8*)op = o;
}

// ---- fp32 transpose 64x64, float4 both sides: [B][4096][256] -> [B][256][4096] ----
__global__ __launch_bounds__(256)
void transpose64_kernel(const float* __restrict__ in, float* __restrict__ out) {
  __shared__ float tile[64][68];
  int cb = blockIdx.x * 64;
  int nb = blockIdx.y * 64;
  int b = blockIdx.z;
  int r = threadIdx.x >> 2, q = threadIdx.x & 3;
  const float* ip = in + ((size_t)b * NPB + nb + r) * 256 + cb;
#pragma unroll
  for (int it = 0; it < 4; ++it) {
    int c = q * 4 + it * 16;
    *(float4*)&tile[r][c] = *(const float4*)(ip + c);
  }
  __syncthreads();
  float* op = out + ((size_t)b * 256 + cb + r) * 4096 + nb;
#pragma unroll
  for (int it = 0; it < 4; ++it) {
    int n = q * 4 + it * 16;
    float4 v;
    v.x = tile[n + 0][r]; v.y = tile[n + 1][r];
    v.z = tile[n + 2][r]; v.w = tile[n + 3][r];
    *(float4*)(op + n) = v;
  }
}

// ---- mask-driven window propagate (bf16 -> bf16), 2 nodes/wave ----
__global__ void prop_kernel(const unsigned short* __restrict__ in,
                            unsigned short* __restrict__ out,
                            const unsigned* __restrict__ mask,
                            const int* __restrict__ deg) {
  int i = blockIdx.x * 8 + (threadIdx.x >> 5);
  int l = threadIdx.x & 31;
  unsigned m = mask[i];
  float a[8] = {};
#pragma unroll
  for (int off = 0; off < 2 * WIN + 1; ++off) {
    int c = ((m >> off) & 1) + (off == WIN);
    if (c) {
      int q = i + off - WIN;
      float dj = (float)c * rsqrtf((float)deg[q]);
      u16x8 u = *(const u16x8*)(in + (size_t)q * 256 + l * 8);
#pragma unroll
      for (int k = 0; k < 8; ++k) a[k] = fmaf(dj, bf2f(u[k]), a[k]);
    }
  }
  float di = rsqrtf((float)deg[i]);
  u16x8 o;
#pragma unroll
  for (int k = 0; k < 8; ++k) o[k] = f2bf(a[k] * di);
  *(u16x8*)(out + (size_t)i * 256 + l * 8) = o;
}

// ---- mask-driven propagate + bias + relu, sorted in -> ORIGINAL-order f32 out ----
__global__ void prop2_kernel(const unsigned short* __restrict__ in,
                             float* __restrict__ out,
                             const unsigned* __restrict__ mask,
                             const int* __restrict__ deg,
                             const float* __restrict__ bias,
                             const unsigned long long* __restrict__ skeys) {
  int i = blockIdx.x * 8 + (threadIdx.x >> 5);
  int l = threadIdx.x & 31;
  unsigned m = mask[i];
  float a[8] = {};
#pragma unroll
  for (int off = 0; off < 2 * WIN + 1; ++off) {
    int c = ((m >> off) & 1) + (off == WIN);
    if (c) {
      int q = i + off - WIN;
      float dj = (float)c * rsqrtf((float)deg[q]);
      u16x8 u = *(const u16x8*)(in + (size_t)q * 256 + l * 8);
#pragma unroll
      for (int k = 0; k < 8; ++k) a[k] = fmaf(dj, bf2f(u[k]), a[k]);
    }
  }
  float di = rsqrtf((float)deg[i]);
  int node = (i & ~(NPB - 1)) + (int)(skeys[i] & 0xffffffffull);   // un-permute
  float4 o0, o1;
  o0.x = fmaxf(a[0] * di + bias[l * 8 + 0], 0.f);
  o0.y = fmaxf(a[1] * di + bias[l * 8 + 1], 0.f);
  o0.z = fmaxf(a[2] * di + bias[l * 8 + 2], 0.f);
  o0.w = fmaxf(a[3] * di + bias[l * 8 + 3], 0.f);
  o1.x = fmaxf(a[4] * di + bias[l * 8 + 4], 0.f);
  o1.y = fmaxf(a[5] * di + bias[l * 8 + 5], 0.f);
  o1.z = fmaxf(a[6] * di + bias[l * 8 + 6], 0.f);
  o1.w = fmaxf(a[7] * di + bias[l * 8 + 7], 0.f);
  *(float4*)(out + (size_t)node * 256 + l * 8) = o0;
  *(float4*)(out + (size_t)node * 256 + l * 8 + 4) = o1;
}

// ---- bf16 MFMA GEMM: C[M,N] = A[M,K] @ Bt[N,K]^T, 64 x (64*NI) tile, BK=64 ----
template <bool BIAS_RELU, bool OUT_BF16, int NI>
__global__ __launch_bounds__(256)
void gemm_bf16_kernel(const unsigned short* __restrict__ A,
                      const unsigned short* __restrict__ Bt,
                      void* __restrict__ C, const float* __restrict__ bias,
                      int M, int N, int K) {
  __shared__ char lds[8192 + NI * 8192];   // A: [64][128B] @0 ; B: [64*NI][128B] @8192
  const int tid = threadIdx.x;
  const int l = tid & 63, w = tid >> 6;
  const int bm = blockIdx.x * 64, bn = blockIdx.y * (64 * NI);
  f32x4 acc[4][NI] = {};

  for (int k0 = 0; k0 < K; k0 += 64) {
    __syncthreads();
#pragma unroll
    for (int q = 0; q < 2; ++q) {          // A tile: 8KB
      int o = q * 4096 + tid * 16;
      int r = o >> 7;
      int gc = ((o >> 4) & 7) ^ (r & 7);
      const char* srcA = (const char*)A + ((size_t)(bm + r) * K + k0) * 2 + gc * 16;
      __builtin_amdgcn_global_load_lds(
          (const __attribute__((address_space(1))) void*)srcA,
          (__attribute__((address_space(3))) void*)(lds + o), 16, 0, 0);
    }
#pragma unroll
    for (int q = 0; q < 2 * NI; ++q) {     // B tile: NI*8KB
      int o = q * 4096 + tid * 16;
      int r = o >> 7;
      int gc = ((o >> 4) & 7) ^ (r & 7);
      const char* srcB = (const char*)Bt + ((size_t)(bn + r) * K + k0) * 2 + gc * 16;
      __builtin_amdgcn_global_load_lds(
          (const __attribute__((address_space(1))) void*)srcB,
          (__attribute__((address_space(3))) void*)(lds + 8192 + o), 16, 0, 0);
    }
    __syncthreads();

#pragma unroll
    for (int kk = 0; kk < 64; kk += 32) {
      bf16x8 af[4], bf[NI];
      int gc = (kk >> 3) + (l >> 4);
#pragma unroll
      for (int mi = 0; mi < 4; ++mi) {
        int r = mi * 16 + (l & 15);
        af[mi] = *(const bf16x8*)(lds + r * 128 + ((gc ^ (r & 7)) << 4));
      }
#pragma unroll
      for (int ni = 0; ni < NI; ++ni) {
        int r = w * (16 * NI) + ni * 16 + (l & 15);
        bf[ni] = *(const bf16x8*)(lds + 8192 + r * 128 + ((gc ^ (r & 7)) << 4));
      }
#pragma unroll
      for (int mi = 0; mi < 4; ++mi)
#pragma unroll
        for (int ni = 0; ni < NI; ++ni)
          acc[mi][ni] = __builtin_amdgcn_mfma_f32_16x16x32_bf16(af[mi], bf[ni],
                                                                acc[mi][ni], 0, 0, 0);
    }
  }

#pragma unroll
  for (int mi = 0; mi < 4; ++mi) {
#pragma unroll
    for (int ni = 0; ni < NI; ++ni) {
      int row0 = bm + mi * 16 + ((l >> 4) << 2);
      int col = bn + w * (16 * NI) + ni * 16 + (l & 15);
      float bv = BIAS_RELU ? bias[col] : 0.f;
      f32x4 v = acc[mi][ni];
#pragma unroll
      for (int r = 0; r < 4; ++r) {
        float val = v[r];
        if (BIAS_RELU) val = fmaxf(val + bv, 0.f);
        if (OUT_BF16)
          ((unsigned short*)C)[(size_t)(row0 + r) * N + col] = f2bf(val);
        else
          ((float*)C)[(size_t)(row0 + r) * N + col] = val;
      }
    }
  }
}

// ---- launch ----
extern "C" void kernel_launch(void* const* d_in, const int* in_sizes, int n_in,
                              void* d_out, int out_size, void* d_ws, size_t ws_size,
                              hipStream_t stream) {
  const float* dm = (const float*)d_in[0];
  const float* fm = (const float*)d_in[1];
  const float* W1 = (const float*)d_in[2];
  const float* b1 = (const float*)d_in[3];
  const float* W2 = (const float*)d_in[4];
  const float* b2 = (const float*)d_in[5];
  float* out = (float*)d_out;

  char* ws = (char*)d_ws;
  int*                deg   = (int*)(ws + 0x040000);               // 64KB
  unsigned*           mask  = (unsigned*)(ws + 0x060000);          // 64KB
  unsigned long long* skeys = (unsigned long long*)(ws + 0x100000);// 128KB
  int*                rank  = (int*)(ws + 0x130000);               // 64KB
  unsigned short*     W1t   = (unsigned short*)(ws + 0x190000);    // 256KB
  unsigned short*     W2t   = (unsigned short*)(ws + 0x1D0000);    // 256KB
  unsigned short*     px0   = (unsigned short*)(ws + 0x0400000);   // 8MB (sorted space)
  unsigned short*     px    = (unsigned short*)(ws + 0x0C00000);   // 8MB (sorted space)
  unsigned short*     h1    = (unsigned short*)(ws + 0x1400000);   // 16MB (sorted space)
  unsigned short*     t2    = (unsigned short*)(ws + 0x2400000);   // 8MB (sorted space)
  float*              xout  = (float*)(ws + 0x2C00000);            // 16MB (original order)
  (void)ws_size; (void)in_sizes; (void)n_in; (void)out_size;

  // graph build: sort (4-CU), then merged {cvt + WIDE select} launch
  bucket_kernel<<<NB, 1024, 0, stream>>>(dm, skeys, rank, deg, mask);
  cvtsel_kernel<<<dim3(128, 4, NB + 1), 256, 0, stream>>>(
      fm, px0, W1, W1t, W2, W2t, rank, skeys, deg, mask);

  // layer 1 (sorted space): mask propagate, then GEMM relu(.@W1+b1) -> bf16
  prop_kernel<<<N_NODES / 8, 256, 0, stream>>>(px0, px, mask, deg);
  gemm_bf16_kernel<true, true, 1><<<dim3(256, 8), 256, 0, stream>>>(
      px, W1t, h1, b1, 16384, 512, 256);

  // layer 2: GEMM h1@W2 -> bf16, mask propagate + un-permute -> f32
  gemm_bf16_kernel<false, true, 1><<<dim3(256, 4), 256, 0, stream>>>(
      h1, W2t, t2, nullptr, 16384, 256, 512);
  prop2_kernel<<<N_NODES / 8, 256, 0, stream>>>(t2, xout, mask, deg, b2, skeys);

  // node-major -> [B][256][4096] (64x64 float4 transpose)
  transpose64_kernel<<<dim3(4, 64, NB), 256, 0, stream>>>(xout, out);
}